// Round 9
// baseline (217.428 us; speedup 1.0000x reference)
//
#include <hip/hip_runtime.h>

#define N_NODES 50000
#define D 128
#define N_EDGES 800000
#define SCAN_BLOCKS ((N_NODES + 255) / 256)   // 196
#define GEMM_BLOCKS ((N_NODES + 63) / 64)     // 782
#define C_BUCKET 48
#define SPILL_CAP 8192
#define HB_PER 512                            // hist blocks per support
#define HIST_TILES ((N_EDGES + 1023) / 1024)  // 782 tiles of 1024 edges

typedef __attribute__((ext_vector_type(8))) short short8;
typedef __attribute__((ext_vector_type(4))) float f32x4;

__device__ __forceinline__ unsigned short f2bf(float f) {
    unsigned u = __builtin_bit_cast(unsigned, f);
    u += 0x7FFFu + ((u >> 16) & 1u);
    return (unsigned short)(u >> 16);
}
__device__ __forceinline__ float bflo(unsigned p) {
    return __builtin_bit_cast(float, p << 16);
}
__device__ __forceinline__ float bfhi(unsigned p) {
    return __builtin_bit_cast(float, p & 0xFFFF0000u);
}

// ---- build wt[s][c][k] bf16 (transposed, c-major) from w[s][k][c] f32 ----
__global__ __launch_bounds__(256) void wt_build(const float* __restrict__ w,
                                                unsigned short* __restrict__ wt) {
    int i = blockIdx.x * 256 + threadIdx.x;
    if (i < 2 * D * D) {
        int s = i >> 14, rem = i & 16383, c = rem >> 7, k = rem & 127;
        wt[i] = f2bf(w[s * D * D + k * D + c]);
    }
}

// ---- gemm body: pre_s = bf16(x @ W_s) for 64 rows starting blk*64 ----
template<int NS>
__device__ __forceinline__ void gemm_body(const float* __restrict__ x,
                                          const unsigned short* __restrict__ wt,
                                          unsigned short* __restrict__ pre0,
                                          unsigned short* __restrict__ pre1,
                                          int n_rows, int blk) {
    const int lane = threadIdx.x & 63;
    const int wid  = threadIdx.x >> 6;
    const int q    = lane >> 4;
    const int rlo  = lane & 15;
    const int r0   = blk * 64 + wid * 16;
    if (r0 >= n_rows) return;

    const float4* x4 = (const float4*)x;
    int arow  = r0 + rlo;
    int arowc = arow < n_rows ? arow : n_rows - 1;

    short8 afr[4];
    #pragma unroll
    for (int kb = 0; kb < 4; ++kb) {
        float4 fa = x4[(size_t)arowc * 32 + kb * 8 + q * 2];
        float4 fb = x4[(size_t)arowc * 32 + kb * 8 + q * 2 + 1];
        short8 a;
        a[0] = (short)f2bf(fa.x); a[1] = (short)f2bf(fa.y);
        a[2] = (short)f2bf(fa.z); a[3] = (short)f2bf(fa.w);
        a[4] = (short)f2bf(fb.x); a[5] = (short)f2bf(fb.y);
        a[6] = (short)f2bf(fb.z); a[7] = (short)f2bf(fb.w);
        afr[kb] = a;
    }

    const short8* wt8 = (const short8*)wt;
    f32x4 acc[NS][8];
    #pragma unroll
    for (int s = 0; s < NS; ++s)
        #pragma unroll
        for (int t = 0; t < 8; ++t)
            acc[s][t] = (f32x4){0.f, 0.f, 0.f, 0.f};

    #pragma unroll
    for (int t = 0; t < 8; ++t) {
        int c = t * 16 + rlo;
        #pragma unroll
        for (int kb = 0; kb < 4; ++kb) {
            short8 b0 = wt8[(size_t)c * 16 + kb * 4 + q];
            acc[0][t] = __builtin_amdgcn_mfma_f32_16x16x32_bf16(afr[kb], b0, acc[0][t], 0, 0, 0);
            if (NS == 2) {
                short8 b1 = wt8[(size_t)(D + c) * 16 + kb * 4 + q];
                acc[1][t] = __builtin_amdgcn_mfma_f32_16x16x32_bf16(afr[kb], b1, acc[1][t], 0, 0, 0);
            }
        }
    }

    #pragma unroll
    for (int i = 0; i < 4; ++i) {
        int rw = r0 + q * 4 + i;
        if (rw < n_rows) {
            #pragma unroll
            for (int t = 0; t < 8; ++t) {
                pre0[(size_t)rw * D + t * 16 + rlo] = f2bf(acc[0][t][i]);
                if (NS == 2) pre1[(size_t)rw * D + t * 16 + rlo] = f2bf(acc[1][t][i]);
            }
        }
    }
}

// ---- K1: [hist+bucket blocks | gemm blocks], all co-resident ----
// hist: 4-edge unrolled independent atomic chains; bucket rec = col<<16 | bf16(val)
__global__ __launch_bounds__(256) void k1_gemm_histbucket(const float* __restrict__ x,
                                                          const unsigned short* __restrict__ wt,
                                                          unsigned short* __restrict__ pre0,
                                                          unsigned short* __restrict__ pre1,
                                                          const int* __restrict__ r0a, const int* __restrict__ c0a,
                                                          const float* __restrict__ v0a,
                                                          const int* __restrict__ r1a, const int* __restrict__ c1a,
                                                          const float* __restrict__ v1a,
                                                          int* __restrict__ cnt,        // [2][N]
                                                          unsigned* __restrict__ bucket,// [2][N][C]
                                                          int* __restrict__ spill_cnt,
                                                          int4* __restrict__ spill,
                                                          int n_rows, int n_edges) {
    int bid = blockIdx.x;
    if (bid < 2 * HB_PER) {
        int s  = bid & 1;
        int vb = bid >> 1;
        const int*   rA = s ? r1a : r0a;
        const int*   cA = s ? c1a : c0a;
        const float* vA = s ? v1a : v0a;
        int* cn = cnt + s * N_NODES;
        unsigned* bk = bucket + (size_t)s * N_NODES * C_BUCKET;
        for (int tile = vb; tile < HIST_TILES; tile += HB_PER) {
            int e0 = tile * 1024 + (int)threadIdx.x;
            int rr[4], cc[4]; float vv[4]; bool ok[4];
            #pragma unroll
            for (int j = 0; j < 4; ++j) {
                int e = e0 + j * 256;
                ok[j] = e < n_edges;
                if (ok[j]) { rr[j] = rA[e]; cc[j] = cA[e]; vv[j] = vA[e]; }
            }
            int slot[4];
            #pragma unroll
            for (int j = 0; j < 4; ++j)
                if (ok[j]) slot[j] = atomicAdd(&cn[rr[j]], 1);
            #pragma unroll
            for (int j = 0; j < 4; ++j) {
                if (ok[j]) {
                    unsigned rec = ((unsigned)cc[j] << 16) | (unsigned)f2bf(vv[j]);
                    if (slot[j] < C_BUCKET) {
                        bk[(size_t)rr[j] * C_BUCKET + slot[j]] = rec;
                    } else {
                        int sp = atomicAdd(spill_cnt, 1);
                        if (sp < SPILL_CAP)
                            spill[sp] = make_int4(rr[j], cc[j], __float_as_int(vv[j]), s);
                    }
                }
            }
        }
    } else {
        gemm_body<2>(x, wt, pre0, pre1, n_rows, bid - 2 * HB_PER);
    }
}

// ---- bucket row accumulate (packed 4B recs) ----
__device__ __forceinline__ void row_acc_bk(const unsigned* __restrict__ bk,
                                           const unsigned* __restrict__ prew,
                                           int i, int e, int lane, float& ax, float& ay) {
    for (; i + 3 < e; i += 4) {
        unsigned R[4], P[4];
        #pragma unroll
        for (int j = 0; j < 4; ++j) R[j] = bk[i + j];
        #pragma unroll
        for (int j = 0; j < 4; ++j) P[j] = prew[(size_t)(R[j] >> 16) * 64 + lane];
        #pragma unroll
        for (int j = 0; j < 4; ++j) {
            float w = bflo(R[j]);
            ax = fmaf(w, bflo(P[j]), ax);
            ay = fmaf(w, bfhi(P[j]), ay);
        }
    }
    for (; i < e; ++i) {
        unsigned r = bk[i];
        float w = bflo(r);
        unsigned p = prew[(size_t)(r >> 16) * 64 + lane];
        ax = fmaf(w, bflo(p), ax);
        ay = fmaf(w, bfhi(p), ay);
    }
}

// ---- gather from buckets: out = relu(A0@pre0 + A1@pre1), one wave per row ----
__global__ __launch_bounds__(256) void gather_bucket(const int* __restrict__ cnt,
                                                     const unsigned* __restrict__ bucket,
                                                     const int* __restrict__ spill_cnt,
                                                     const int4* __restrict__ spill,
                                                     const unsigned short* __restrict__ pre0,
                                                     const unsigned short* __restrict__ pre1,
                                                     float* __restrict__ out, int n_rows) {
    const int lane = threadIdx.x & 63;
    const int wid  = threadIdx.x >> 6;
    const int wpg  = 4 * gridDim.x;
    const unsigned* pre0w = (const unsigned*)pre0;
    const unsigned* pre1w = (const unsigned*)pre1;
    float2* out2 = (float2*)out;
    int K = *spill_cnt;
    K = K < SPILL_CAP ? K : SPILL_CAP;

    for (int r = blockIdx.x * 4 + wid; r < n_rows; r += wpg) {
        int cn0 = cnt[r];            cn0 = cn0 < C_BUCKET ? cn0 : C_BUCKET;
        int cn1 = cnt[N_NODES + r];  cn1 = cn1 < C_BUCKET ? cn1 : C_BUCKET;
        const unsigned* b0 = bucket + (size_t)r * C_BUCKET;
        const unsigned* b1 = bucket + (size_t)(N_NODES + r) * C_BUCKET;
        float ax0 = 0.f, ay0 = 0.f, ax1 = 0.f, ay1 = 0.f;
        int i0 = 0, i1 = 0;
        // joint 8-deep: both supports' random reads in flight together
        while (i0 + 3 < cn0 && i1 + 3 < cn1) {
            unsigned R0[4], R1[4], P0[4], P1[4];
            #pragma unroll
            for (int j = 0; j < 4; ++j) { R0[j] = b0[i0 + j]; R1[j] = b1[i1 + j]; }
            #pragma unroll
            for (int j = 0; j < 4; ++j) {
                P0[j] = pre0w[(size_t)(R0[j] >> 16) * 64 + lane];
                P1[j] = pre1w[(size_t)(R1[j] >> 16) * 64 + lane];
            }
            #pragma unroll
            for (int j = 0; j < 4; ++j) {
                float w0 = bflo(R0[j]);
                float w1 = bflo(R1[j]);
                ax0 = fmaf(w0, bflo(P0[j]), ax0);
                ay0 = fmaf(w0, bfhi(P0[j]), ay0);
                ax1 = fmaf(w1, bflo(P1[j]), ax1);
                ay1 = fmaf(w1, bfhi(P1[j]), ay1);
            }
            i0 += 4; i1 += 4;
        }
        row_acc_bk(b0, pre0w, i0, cn0, lane, ax0, ay0);
        row_acc_bk(b1, pre1w, i1, cn1, lane, ax1, ay1);
        // spill safety net (K == 0 in practice)
        for (int k = 0; k < K; ++k) {
            int4 sp = spill[k];
            if (sp.x == r) {
                float w = __int_as_float(sp.z);
                const unsigned* pw = sp.w ? pre1w : pre0w;
                unsigned p = pw[(size_t)sp.y * 64 + lane];
                if (sp.w) { ax1 = fmaf(w, bflo(p), ax1); ay1 = fmaf(w, bfhi(p), ay1); }
                else      { ax0 = fmaf(w, bflo(p), ax0); ay0 = fmaf(w, bfhi(p), ay0); }
            }
        }
        float2 o;
        o.x = fmaxf(ax0 + ax1, 0.f);
        o.y = fmaxf(ay0 + ay1, 0.f);
        out2[(size_t)r * 64 + lane] = o;
    }
}

// ================= fallback path (R7 tier-A1, proven) =================
__global__ __launch_bounds__(256) void gemm_mfma2(const float* __restrict__ x,
                                                  const unsigned short* __restrict__ wt,
                                                  unsigned short* __restrict__ pre0,
                                                  unsigned short* __restrict__ pre1, int n_rows) {
    gemm_body<2>(x, wt, pre0, pre1, n_rows, blockIdx.x);
}
__global__ __launch_bounds__(256) void gemm_mfma1(const float* __restrict__ x,
                                                  const unsigned short* __restrict__ wt,
                                                  unsigned short* __restrict__ pre, int n_rows) {
    gemm_body<1>(x, wt, pre, pre, n_rows, blockIdx.x);
}

__global__ __launch_bounds__(256) void hist_rank(const int* __restrict__ r0,
                                                 const int* __restrict__ r1,
                                                 int* __restrict__ cnt_base,
                                                 int* __restrict__ rank_base, int n_edges) {
    int s = blockIdx.y;
    const int* r = s ? r1 : r0;
    int* cnt  = cnt_base + s * N_NODES;
    int* rank = rank_base + (size_t)s * N_EDGES;
    for (int e = blockIdx.x * 256 + threadIdx.x; e < n_edges; e += gridDim.x * 256)
        rank[e] = atomicAdd(&cnt[r[e]], 1);
}

__global__ __launch_bounds__(256) void scanA(const int* __restrict__ tot_base,
                                             int* __restrict__ bsum) {
    int s = blockIdx.y;
    int i = blockIdx.x * 256 + threadIdx.x;
    int v = (i < N_NODES) ? tot_base[s * N_NODES + i] : 0;
    const int lane = threadIdx.x & 63;
    const int wid  = threadIdx.x >> 6;
    __shared__ int ws[4];
    #pragma unroll
    for (int off = 32; off > 0; off >>= 1) v += __shfl_down(v, off);
    if (lane == 0) ws[wid] = v;
    __syncthreads();
    if (threadIdx.x == 0)
        bsum[s * SCAN_BLOCKS + blockIdx.x] = ws[0] + ws[1] + ws[2] + ws[3];
}

__global__ __launch_bounds__(256) void scanB(int* __restrict__ bsum) {
    int s = blockIdx.x;
    int t = threadIdx.x;
    int v = (t < SCAN_BLOCKS) ? bsum[s * SCAN_BLOCKS + t] : 0;
    const int lane = t & 63;
    const int wid  = t >> 6;
    __shared__ int ws[4];
    int incl = v;
    #pragma unroll
    for (int off = 1; off < 64; off <<= 1) {
        int tv = __shfl_up(incl, off);
        if (lane >= off) incl += tv;
    }
    if (lane == 63) ws[wid] = incl;
    __syncthreads();
    int wbase = 0;
    #pragma unroll
    for (int j = 0; j < 4; ++j) wbase += (j < wid) ? ws[j] : 0;
    if (t < SCAN_BLOCKS) bsum[s * SCAN_BLOCKS + t] = wbase + incl - v;
}

__global__ __launch_bounds__(256) void scanC(const int* __restrict__ tot_base,
                                             const int* __restrict__ bsum,
                                             int* __restrict__ off_base) {
    int s = blockIdx.y;
    int i = blockIdx.x * 256 + threadIdx.x;
    int v = (i < N_NODES) ? tot_base[s * N_NODES + i] : 0;
    const int lane = threadIdx.x & 63;
    const int wid  = threadIdx.x >> 6;
    __shared__ int ws[4];
    int incl = v;
    #pragma unroll
    for (int off = 1; off < 64; off <<= 1) {
        int tv = __shfl_up(incl, off);
        if (lane >= off) incl += tv;
    }
    if (lane == 63) ws[wid] = incl;
    __syncthreads();
    int wbase = 0;
    #pragma unroll
    for (int j = 0; j < 4; ++j) wbase += (j < wid) ? ws[j] : 0;
    int* off = off_base + s * (N_NODES + 1);
    if (i < N_NODES)
        off[i] = bsum[s * SCAN_BLOCKS + blockIdx.x] + wbase + incl - v;
    if (blockIdx.x == 0 && threadIdx.x == 0)
        off[N_NODES] = N_EDGES;
}

__global__ __launch_bounds__(256) void scatter_csr(const int* __restrict__ r0, const int* __restrict__ c0,
                                                   const float* __restrict__ v0,
                                                   const int* __restrict__ r1, const int* __restrict__ c1,
                                                   const float* __restrict__ v1,
                                                   const int* __restrict__ off_base,
                                                   const int* __restrict__ rank_base,
                                                   int2* __restrict__ ep_base, int n_edges) {
    int s = blockIdx.y;
    const int*   r    = s ? r1 : r0;
    const int*   c    = s ? c1 : c0;
    const float* v    = s ? v1 : v0;
    const int*   off  = off_base + s * (N_NODES + 1);
    const int*   rank = rank_base + (size_t)s * N_EDGES;
    int2* ep = ep_base + (size_t)s * N_EDGES;
    for (int e = blockIdx.x * 256 + threadIdx.x; e < n_edges; e += gridDim.x * 256) {
        int p = off[r[e]] + rank[e];
        int2 rec;
        rec.x = c[e];
        rec.y = __float_as_int(v[e]);
        ep[p] = rec;
    }
}

__device__ __forceinline__ void row_acc(const int2* __restrict__ ep,
                                        const unsigned short* __restrict__ pre,
                                        int b, int e, int lane, float& ax, float& ay) {
    int i = b;
    for (; i + 3 < e; i += 4) {
        int2 E[4];
        unsigned P[4];
        #pragma unroll
        for (int j = 0; j < 4; ++j) E[j] = ep[i + j];
        #pragma unroll
        for (int j = 0; j < 4; ++j) P[j] = *(const unsigned*)(pre + (size_t)E[j].x * D + 2 * lane);
        #pragma unroll
        for (int j = 0; j < 4; ++j) {
            float w = __int_as_float(E[j].y);
            ax = fmaf(w, bflo(P[j]), ax);
            ay = fmaf(w, bfhi(P[j]), ay);
        }
        i += 0;
    }
    for (; i < e; ++i) {
        int2 e0 = ep[i];
        float w = __int_as_float(e0.y);
        unsigned p = *(const unsigned*)(pre + (size_t)e0.x * D + 2 * lane);
        ax = fmaf(w, bflo(p), ax);
        ay = fmaf(w, bfhi(p), ay);
    }
}

__global__ __launch_bounds__(256) void gather_fused(const int* __restrict__ off_base,
                                                    const int2* __restrict__ ep_base,
                                                    const unsigned short* __restrict__ pre0,
                                                    const unsigned short* __restrict__ pre1,
                                                    float* __restrict__ out, int n_rows) {
    const int lane = threadIdx.x & 63;
    const int wid  = threadIdx.x >> 6;
    const int wpg  = 4 * gridDim.x;
    const int* o1 = off_base + (N_NODES + 1);
    float2* out2 = (float2*)out;
    for (int r = blockIdx.x * 4 + wid; r < n_rows; r += wpg) {
        float ax0 = 0.f, ay0 = 0.f, ax1 = 0.f, ay1 = 0.f;
        row_acc(ep_base, pre0, off_base[r], off_base[r + 1], lane, ax0, ay0);
        row_acc(ep_base + N_EDGES, pre1, o1[r], o1[r + 1], lane, ax1, ay1);
        float2 o;
        o.x = fmaxf(ax0 + ax1, 0.f);
        o.y = fmaxf(ay0 + ay1, 0.f);
        out2[(size_t)r * 64 + lane] = o;
    }
}

template<int ACCUM_RELU>
__global__ __launch_bounds__(256) void gather_one(const int* __restrict__ off,
                                                  const int2* __restrict__ ep,
                                                  const unsigned short* __restrict__ pre,
                                                  float* __restrict__ out, int n_rows) {
    const int lane = threadIdx.x & 63;
    const int wid  = threadIdx.x >> 6;
    const int wpg  = 4 * gridDim.x;
    float2* out2 = (float2*)out;
    for (int r = blockIdx.x * 4 + wid; r < n_rows; r += wpg) {
        float ax = 0.f, ay = 0.f;
        row_acc(ep, pre, off[r], off[r + 1], lane, ax, ay);
        float2 o;
        if (ACCUM_RELU) {
            float2 prev = out2[(size_t)r * 64 + lane];
            o.x = fmaxf(prev.x + ax, 0.f);
            o.y = fmaxf(prev.y + ay, 0.f);
        } else {
            o.x = ax; o.y = ay;
        }
        out2[(size_t)r * 64 + lane] = o;
    }
}

extern "C" void kernel_launch(void* const* d_in, const int* in_sizes, int n_in,
                              void* d_out, int out_size, void* d_ws, size_t ws_size,
                              hipStream_t stream) {
    const float* x       = (const float*)d_in[0];
    const float* weights = (const float*)d_in[1];
    const int*   ei0     = (const int*)d_in[2];
    const float* v0      = (const float*)d_in[3];
    const int*   ei1     = (const int*)d_in[4];
    const float* v1      = (const float*)d_in[5];
    float* out = (float*)d_out;

    dim3 blk(256);
    const size_t PRE_B = (size_t)N_NODES * D * sizeof(unsigned short);  // 12.8 MB
    const size_t WT_B  = (size_t)2 * D * D * sizeof(unsigned short);    // 64 KB

    char* wsb = (char*)d_ws;
    // bucket tier: pre0, pre1, wt, cnt[2N], spill_cnt(16B), spill[SPILL_CAP], bucket[2N*C]
    size_t needBK = PRE_B * 2 + WT_B + (size_t)2 * N_NODES * 4 + 16
                  + (size_t)SPILL_CAP * 16 + (size_t)2 * N_NODES * C_BUCKET * 4;
    // fallback tier (R7-A1): pre0, pre1, wt, off[2(N+1)], cnt[2N], bsum[2SB], ep[2E], rank[2E]
    size_t needA1 = PRE_B * 2 + WT_B
                  + (size_t)(2 * (N_NODES + 1) + 2 * N_NODES + 2 * SCAN_BLOCKS) * 4
                  + (size_t)2 * N_EDGES * sizeof(int2) + (size_t)2 * N_EDGES * 4;

    if (ws_size >= needBK) {
        unsigned short* pre0 = (unsigned short*)wsb;
        unsigned short* pre1 = (unsigned short*)(wsb + PRE_B);
        unsigned short* wt   = (unsigned short*)(wsb + 2 * PRE_B);
        int*      cnt       = (int*)(wsb + 2 * PRE_B + WT_B);
        int*      spill_cnt = cnt + 2 * N_NODES;                  // 16B slot
        int4*     spill     = (int4*)((char*)spill_cnt + 16);
        unsigned* bucket    = (unsigned*)(spill + SPILL_CAP);

        hipMemsetAsync(cnt, 0, (size_t)2 * N_NODES * 4 + 16, stream);  // cnt + spill_cnt
        wt_build<<<128, blk, 0, stream>>>(weights, wt);
        k1_gemm_histbucket<<<2 * HB_PER + GEMM_BLOCKS, blk, 0, stream>>>(
            x, wt, pre0, pre1,
            ei0, ei0 + N_EDGES, v0, ei1, ei1 + N_EDGES, v1,
            cnt, bucket, spill_cnt, spill, N_NODES, N_EDGES);
        gather_bucket<<<12500, blk, 0, stream>>>(cnt, bucket, spill_cnt, spill,
                                                 pre0, pre1, out, N_NODES);
    } else if (ws_size >= needA1) {
        unsigned short* pre0 = (unsigned short*)wsb;
        unsigned short* pre1 = (unsigned short*)(wsb + PRE_B);
        unsigned short* wt   = (unsigned short*)(wsb + 2 * PRE_B);
        int*  off  = (int*)(wsb + 2 * PRE_B + WT_B);
        int*  cnt  = off + 2 * (N_NODES + 1);
        int*  bsum = cnt + 2 * N_NODES;
        int2* ep   = (int2*)(bsum + 2 * SCAN_BLOCKS);
        int*  rank = (int*)(ep + (size_t)2 * N_EDGES);

        hipMemsetAsync(cnt, 0, (size_t)2 * N_NODES * sizeof(int), stream);
        wt_build<<<128, blk, 0, stream>>>(weights, wt);
        hist_rank<<<dim3(1024, 2), blk, 0, stream>>>(ei0, ei1, cnt, rank, N_EDGES);
        gemm_mfma2<<<GEMM_BLOCKS, blk, 0, stream>>>(x, wt, pre0, pre1, N_NODES);
        scanA<<<dim3(SCAN_BLOCKS, 2), blk, 0, stream>>>(cnt, bsum);
        scanB<<<2, blk, 0, stream>>>(bsum);
        scanC<<<dim3(SCAN_BLOCKS, 2), blk, 0, stream>>>(cnt, bsum, off);
        scatter_csr<<<dim3(1024, 2), blk, 0, stream>>>(ei0, ei0 + N_EDGES, v0,
                                                       ei1, ei1 + N_EDGES, v1,
                                                       off, rank, ep, N_EDGES);
        gather_fused<<<12500, blk, 0, stream>>>(off, ep, pre0, pre1, out, N_NODES);
    } else {
        // minimal sequential path
        unsigned short* pre = (unsigned short*)wsb;
        unsigned short* wt  = (unsigned short*)(wsb + PRE_B);
        int*  off  = (int*)(wsb + PRE_B + WT_B);
        int*  cnt  = off + (N_NODES + 1);
        int*  bsum = cnt + N_NODES;
        int2* ep   = (int2*)(bsum + SCAN_BLOCKS);
        int*  rank = (int*)pre;

        wt_build<<<128, blk, 0, stream>>>(weights, wt);
        const int* rows[2] = {ei0, ei1};
        const int* cols[2] = {ei0 + N_EDGES, ei1 + N_EDGES};
        const float* vals[2] = {v0, v1};
        for (int s = 0; s < 2; ++s) {
            hipMemsetAsync(cnt, 0, (size_t)N_NODES * sizeof(int), stream);
            hist_rank<<<dim3(1024, 1), blk, 0, stream>>>(rows[s], rows[s], cnt, rank, N_EDGES);
            scanA<<<dim3(SCAN_BLOCKS, 1), blk, 0, stream>>>(cnt, bsum);
            scanB<<<1, blk, 0, stream>>>(bsum);
            scanC<<<dim3(SCAN_BLOCKS, 1), blk, 0, stream>>>(cnt, bsum, off);
            scatter_csr<<<dim3(1024, 1), blk, 0, stream>>>(rows[s], cols[s], vals[s],
                                                           rows[s], cols[s], vals[s],
                                                           off, rank, ep, N_EDGES);
            gemm_mfma1<<<GEMM_BLOCKS, blk, 0, stream>>>(x, wt + (size_t)s * D * D, pre, N_NODES);
            if (s == 0)
                gather_one<0><<<12500, blk, 0, stream>>>(off, ep, pre, out, N_NODES);
            else
                gather_one<1><<<12500, blk, 0, stream>>>(off, ep, pre, out, N_NODES);
        }
    }
}

// Round 10
// 209.430 us; speedup vs baseline: 1.0382x; 1.0382x over previous
//
#include <hip/hip_runtime.h>

#define N_NODES 50000
#define D 128
#define N_EDGES 800000
#define SCAN_BLOCKS ((N_NODES + 255) / 256)   // 196
#define GEMM_BLOCKS ((N_NODES + 63) / 64)     // 782
#define HB_PER 632                            // hist blocks per support
#define HB_TOTAL (2 * HB_PER)                 // 1264; +782 gemm = 2046 <= ~2048 resident

typedef __attribute__((ext_vector_type(8))) short short8;
typedef __attribute__((ext_vector_type(4))) float f32x4;

__device__ __forceinline__ unsigned short f2bf(float f) {
    unsigned u = __builtin_bit_cast(unsigned, f);
    u += 0x7FFFu + ((u >> 16) & 1u);
    return (unsigned short)(u >> 16);
}
__device__ __forceinline__ float bflo(unsigned p) {
    return __builtin_bit_cast(float, p << 16);
}
__device__ __forceinline__ float bfhi(unsigned p) {
    return __builtin_bit_cast(float, p & 0xFFFF0000u);
}

// ---- build wt[s][c][k] bf16 (transposed, c-major) from w[s][k][c] f32 ----
__global__ __launch_bounds__(256) void wt_build(const float* __restrict__ w,
                                                unsigned short* __restrict__ wt) {
    int i = blockIdx.x * 256 + threadIdx.x;
    if (i < 2 * D * D) {
        int s = i >> 14, rem = i & 16383, c = rem >> 7, k = rem & 127;
        wt[i] = f2bf(w[s * D * D + k * D + c]);
    }
}

// ---- gemm body: pre_s = bf16(x @ W_s) for 64 rows starting blk*64 ----
template<int NS>
__device__ __forceinline__ void gemm_body(const float* __restrict__ x,
                                          const unsigned short* __restrict__ wt,
                                          unsigned short* __restrict__ pre0,
                                          unsigned short* __restrict__ pre1,
                                          int n_rows, int blk) {
    const int lane = threadIdx.x & 63;
    const int wid  = threadIdx.x >> 6;
    const int q    = lane >> 4;
    const int rlo  = lane & 15;
    const int r0   = blk * 64 + wid * 16;
    if (r0 >= n_rows) return;

    const float4* x4 = (const float4*)x;
    int arow  = r0 + rlo;
    int arowc = arow < n_rows ? arow : n_rows - 1;

    short8 afr[4];
    #pragma unroll
    for (int kb = 0; kb < 4; ++kb) {
        float4 fa = x4[(size_t)arowc * 32 + kb * 8 + q * 2];
        float4 fb = x4[(size_t)arowc * 32 + kb * 8 + q * 2 + 1];
        short8 a;
        a[0] = (short)f2bf(fa.x); a[1] = (short)f2bf(fa.y);
        a[2] = (short)f2bf(fa.z); a[3] = (short)f2bf(fa.w);
        a[4] = (short)f2bf(fb.x); a[5] = (short)f2bf(fb.y);
        a[6] = (short)f2bf(fb.z); a[7] = (short)f2bf(fb.w);
        afr[kb] = a;
    }

    const short8* wt8 = (const short8*)wt;
    f32x4 acc[NS][8];
    #pragma unroll
    for (int s = 0; s < NS; ++s)
        #pragma unroll
        for (int t = 0; t < 8; ++t)
            acc[s][t] = (f32x4){0.f, 0.f, 0.f, 0.f};

    #pragma unroll
    for (int t = 0; t < 8; ++t) {
        int c = t * 16 + rlo;
        #pragma unroll
        for (int kb = 0; kb < 4; ++kb) {
            short8 b0 = wt8[(size_t)c * 16 + kb * 4 + q];
            acc[0][t] = __builtin_amdgcn_mfma_f32_16x16x32_bf16(afr[kb], b0, acc[0][t], 0, 0, 0);
            if (NS == 2) {
                short8 b1 = wt8[(size_t)(D + c) * 16 + kb * 4 + q];
                acc[1][t] = __builtin_amdgcn_mfma_f32_16x16x32_bf16(afr[kb], b1, acc[1][t], 0, 0, 0);
            }
        }
    }

    #pragma unroll
    for (int i = 0; i < 4; ++i) {
        int rw = r0 + q * 4 + i;
        if (rw < n_rows) {
            #pragma unroll
            for (int t = 0; t < 8; ++t) {
                pre0[(size_t)rw * D + t * 16 + rlo] = f2bf(acc[0][t][i]);
                if (NS == 2) pre1[(size_t)rw * D + t * 16 + rlo] = f2bf(acc[1][t][i]);
            }
        }
    }
}

// ---- K1: [hist blocks | gemm blocks], fully co-resident ----
// hist: 4 independent atomic chains in flight per thread; rank store coalesced.
__global__ __launch_bounds__(256) void k1_gemm_hist(const float* __restrict__ x,
                                                    const unsigned short* __restrict__ wt,
                                                    unsigned short* __restrict__ pre0,
                                                    unsigned short* __restrict__ pre1,
                                                    const int* __restrict__ r0,
                                                    const int* __restrict__ r1,
                                                    int* __restrict__ cnt_base,
                                                    int* __restrict__ rank_base,
                                                    int n_rows, int n_edges) {
    int bid = blockIdx.x;
    if (bid < HB_TOTAL) {
        int s  = bid & 1;
        int vb = bid >> 1;
        const int* r = s ? r1 : r0;
        int* cnt  = cnt_base + s * N_NODES;
        int* rank = rank_base + (size_t)s * N_EDGES;
        const int STR = HB_PER * 256;
        for (int eb = vb * 256 + (int)threadIdx.x; eb < n_edges; eb += 4 * STR) {
            int ee[4], rr[4], slot[4];
            bool ok[4];
            #pragma unroll
            for (int j = 0; j < 4; ++j) {
                ee[j] = eb + j * STR;
                ok[j] = ee[j] < n_edges;
                if (ok[j]) rr[j] = r[ee[j]];
            }
            #pragma unroll
            for (int j = 0; j < 4; ++j)
                if (ok[j]) slot[j] = atomicAdd(&cnt[rr[j]], 1);
            #pragma unroll
            for (int j = 0; j < 4; ++j)
                if (ok[j]) rank[ee[j]] = slot[j];
        }
    } else {
        gemm_body<2>(x, wt, pre0, pre1, n_rows, bid - HB_TOTAL);
    }
}

// ---- standalone pieces for fallback paths ----
__global__ __launch_bounds__(256) void gemm_mfma2(const float* __restrict__ x,
                                                  const unsigned short* __restrict__ wt,
                                                  unsigned short* __restrict__ pre0,
                                                  unsigned short* __restrict__ pre1, int n_rows) {
    gemm_body<2>(x, wt, pre0, pre1, n_rows, blockIdx.x);
}
__global__ __launch_bounds__(256) void gemm_mfma1(const float* __restrict__ x,
                                                  const unsigned short* __restrict__ wt,
                                                  unsigned short* __restrict__ pre, int n_rows) {
    gemm_body<1>(x, wt, pre, pre, n_rows, blockIdx.x);
}

__global__ __launch_bounds__(256) void hist_rank(const int* __restrict__ r0,
                                                 const int* __restrict__ r1,
                                                 int* __restrict__ cnt_base,
                                                 int* __restrict__ rank_base, int n_edges) {
    int s = blockIdx.y;
    const int* r = s ? r1 : r0;
    int* cnt  = cnt_base + s * N_NODES;
    int* rank = rank_base + (size_t)s * N_EDGES;
    for (int e = blockIdx.x * 256 + threadIdx.x; e < n_edges; e += gridDim.x * 256)
        rank[e] = atomicAdd(&cnt[r[e]], 1);
}

// ---- scanA: per-block sums of cnt ----
__global__ __launch_bounds__(256) void scanA(const int* __restrict__ cnt_base,
                                             int* __restrict__ bsum) {
    int s = blockIdx.y;
    int i = blockIdx.x * 256 + threadIdx.x;
    int v = (i < N_NODES) ? cnt_base[s * N_NODES + i] : 0;
    const int lane = threadIdx.x & 63;
    const int wid  = threadIdx.x >> 6;
    __shared__ int ws[4];
    #pragma unroll
    for (int off = 32; off > 0; off >>= 1) v += __shfl_down(v, off);
    if (lane == 0) ws[wid] = v;
    __syncthreads();
    if (threadIdx.x == 0)
        bsum[s * SCAN_BLOCKS + blockIdx.x] = ws[0] + ws[1] + ws[2] + ws[3];
}

// ---- scanC2: block base = in-block reduction of earlier bsums; local scan; write off ----
__global__ __launch_bounds__(256) void scanC2(const int* __restrict__ cnt_base,
                                              const int* __restrict__ bsum,
                                              int* __restrict__ off_base) {
    int s = blockIdx.y;
    int t = threadIdx.x;
    const int lane = t & 63;
    const int wid  = t >> 6;
    __shared__ int ws[4];
    __shared__ int base_s;

    // block base: sum of bsum[s][j] for j < blockIdx.x
    int bv = (t < (int)blockIdx.x && t < SCAN_BLOCKS) ? bsum[s * SCAN_BLOCKS + t] : 0;
    #pragma unroll
    for (int off = 32; off > 0; off >>= 1) bv += __shfl_down(bv, off);
    if (lane == 0) ws[wid] = bv;
    __syncthreads();
    if (t == 0) base_s = ws[0] + ws[1] + ws[2] + ws[3];
    __syncthreads();
    int base = base_s;
    __syncthreads();

    // local exclusive scan of this block's 256 counts
    int i = blockIdx.x * 256 + t;
    int v = (i < N_NODES) ? cnt_base[s * N_NODES + i] : 0;
    int incl = v;
    #pragma unroll
    for (int off = 1; off < 64; off <<= 1) {
        int tv = __shfl_up(incl, off);
        if (lane >= off) incl += tv;
    }
    if (lane == 63) ws[wid] = incl;
    __syncthreads();
    int wbase = 0;
    #pragma unroll
    for (int j = 0; j < 4; ++j) wbase += (j < wid) ? ws[j] : 0;
    int* off = off_base + s * (N_NODES + 1);
    if (i < N_NODES)
        off[i] = base + wbase + incl - v;
    if (blockIdx.x == 0 && t == 0)
        off[N_NODES] = N_EDGES;
}

// ---- CSR scatter: no atomics, fire-and-forget 8B stores (y-dim = support) ----
__global__ __launch_bounds__(256) void scatter_csr(const int* __restrict__ r0, const int* __restrict__ c0,
                                                   const float* __restrict__ v0,
                                                   const int* __restrict__ r1, const int* __restrict__ c1,
                                                   const float* __restrict__ v1,
                                                   const int* __restrict__ off_base,
                                                   const int* __restrict__ rank_base,
                                                   int2* __restrict__ ep_base, int n_edges) {
    int s = blockIdx.y;
    const int*   r    = s ? r1 : r0;
    const int*   c    = s ? c1 : c0;
    const float* v    = s ? v1 : v0;
    const int*   off  = off_base + s * (N_NODES + 1);
    const int*   rank = rank_base + (size_t)s * N_EDGES;
    int2* ep = ep_base + (size_t)s * N_EDGES;
    for (int e = blockIdx.x * 256 + threadIdx.x; e < n_edges; e += gridDim.x * 256) {
        int p = off[r[e]] + rank[e];
        int2 rec;
        rec.x = c[e];
        rec.y = __float_as_int(v[e]);
        ep[p] = rec;
    }
}

// ---- row accumulate: unroll-8 pipelined random reads ----
__device__ __forceinline__ void row_acc(const int2* __restrict__ ep,
                                        const unsigned short* __restrict__ pre,
                                        int b, int e, int lane, float& ax, float& ay) {
    int i = b;
    for (; i + 7 < e; i += 8) {
        int2 E[8];
        unsigned P[8];
        #pragma unroll
        for (int j = 0; j < 8; ++j) E[j] = ep[i + j];
        #pragma unroll
        for (int j = 0; j < 8; ++j) P[j] = *(const unsigned*)(pre + (size_t)E[j].x * D + 2 * lane);
        #pragma unroll
        for (int j = 0; j < 8; ++j) {
            float w = __int_as_float(E[j].y);
            ax = fmaf(w, bflo(P[j]), ax);
            ay = fmaf(w, bfhi(P[j]), ay);
        }
    }
    if (i + 3 < e) {
        int2 E[4];
        unsigned P[4];
        #pragma unroll
        for (int j = 0; j < 4; ++j) E[j] = ep[i + j];
        #pragma unroll
        for (int j = 0; j < 4; ++j) P[j] = *(const unsigned*)(pre + (size_t)E[j].x * D + 2 * lane);
        #pragma unroll
        for (int j = 0; j < 4; ++j) {
            float w = __int_as_float(E[j].y);
            ax = fmaf(w, bflo(P[j]), ax);
            ay = fmaf(w, bfhi(P[j]), ay);
        }
        i += 4;
    }
    for (; i < e; ++i) {
        int2 e0 = ep[i];
        float w = __int_as_float(e0.y);
        unsigned p = *(const unsigned*)(pre + (size_t)e0.x * D + 2 * lane);
        ax = fmaf(w, bflo(p), ax);
        ay = fmaf(w, bfhi(p), ay);
    }
}

// ---- fused gather, dual-support interleaved loads ----
__global__ __launch_bounds__(256) void gather_fused(const int* __restrict__ off_base,
                                                    const int2* __restrict__ ep_base,
                                                    const unsigned short* __restrict__ pre0,
                                                    const unsigned short* __restrict__ pre1,
                                                    float* __restrict__ out, int n_rows) {
    const int lane = threadIdx.x & 63;
    const int wid  = threadIdx.x >> 6;
    const int wpg  = 4 * gridDim.x;
    const int2* ep1b = ep_base + N_EDGES;
    const int* o1 = off_base + (N_NODES + 1);
    float2* out2 = (float2*)out;
    for (int r = blockIdx.x * 4 + wid; r < n_rows; r += wpg) {
        float ax0 = 0.f, ay0 = 0.f, ax1 = 0.f, ay1 = 0.f;
        int i0 = off_base[r], e0 = off_base[r + 1];
        int i1 = o1[r],       e1 = o1[r + 1];
        while (i0 + 7 < e0 && i1 + 7 < e1) {
            int2 E0[8], E1[8];
            unsigned P0[8], P1[8];
            #pragma unroll
            for (int j = 0; j < 8; ++j) { E0[j] = ep_base[i0 + j]; E1[j] = ep1b[i1 + j]; }
            #pragma unroll
            for (int j = 0; j < 8; ++j) {
                P0[j] = *(const unsigned*)(pre0 + (size_t)E0[j].x * D + 2 * lane);
                P1[j] = *(const unsigned*)(pre1 + (size_t)E1[j].x * D + 2 * lane);
            }
            #pragma unroll
            for (int j = 0; j < 8; ++j) {
                float w0 = __int_as_float(E0[j].y);
                float w1 = __int_as_float(E1[j].y);
                ax0 = fmaf(w0, bflo(P0[j]), ax0);
                ay0 = fmaf(w0, bfhi(P0[j]), ay0);
                ax1 = fmaf(w1, bflo(P1[j]), ax1);
                ay1 = fmaf(w1, bfhi(P1[j]), ay1);
            }
            i0 += 8; i1 += 8;
        }
        row_acc(ep_base, pre0, i0, e0, lane, ax0, ay0);
        row_acc(ep1b,    pre1, i1, e1, lane, ax1, ay1);
        float2 o;
        o.x = fmaxf(ax0 + ax1, 0.f);
        o.y = fmaxf(ay0 + ay1, 0.f);
        out2[(size_t)r * 64 + lane] = o;
    }
}

// ---- single-support gather (sequential fallback) ----
template<int ACCUM_RELU>
__global__ __launch_bounds__(256) void gather_one(const int* __restrict__ off,
                                                  const int2* __restrict__ ep,
                                                  const unsigned short* __restrict__ pre,
                                                  float* __restrict__ out, int n_rows) {
    const int lane = threadIdx.x & 63;
    const int wid  = threadIdx.x >> 6;
    const int wpg  = 4 * gridDim.x;
    float2* out2 = (float2*)out;
    for (int r = blockIdx.x * 4 + wid; r < n_rows; r += wpg) {
        float ax = 0.f, ay = 0.f;
        row_acc(ep, pre, off[r], off[r + 1], lane, ax, ay);
        float2 o;
        if (ACCUM_RELU) {
            float2 prev = out2[(size_t)r * 64 + lane];
            o.x = fmaxf(prev.x + ax, 0.f);
            o.y = fmaxf(prev.y + ay, 0.f);
        } else {
            o.x = ax; o.y = ay;
        }
        out2[(size_t)r * 64 + lane] = o;
    }
}

extern "C" void kernel_launch(void* const* d_in, const int* in_sizes, int n_in,
                              void* d_out, int out_size, void* d_ws, size_t ws_size,
                              hipStream_t stream) {
    const float* x       = (const float*)d_in[0];
    const float* weights = (const float*)d_in[1];
    const int*   ei0     = (const int*)d_in[2];
    const float* v0      = (const float*)d_in[3];
    const int*   ei1     = (const int*)d_in[4];
    const float* v1      = (const float*)d_in[5];
    float* out = (float*)d_out;

    dim3 blk(256);
    const size_t PRE_B = (size_t)N_NODES * D * sizeof(unsigned short);  // 12.8 MB
    const size_t WT_B  = (size_t)2 * D * D * sizeof(unsigned short);    // 64 KB

    char* wsb = (char*)d_ws;
    // tier A1: pre0, pre1, wt, off[2(N+1)], cnt[2N], bsum[2SB], ep[2E], rank[2E]
    size_t needA1 = PRE_B * 2 + WT_B
                  + (size_t)(2 * (N_NODES + 1) + 2 * N_NODES + 2 * SCAN_BLOCKS) * 4
                  + (size_t)2 * N_EDGES * sizeof(int2) + (size_t)2 * N_EDGES * 4;
    // tier B: same minus rank (rank aliases pre0, serial schedule)
    size_t needB = needA1 - (size_t)2 * N_EDGES * 4;

    if (ws_size >= needA1) {
        unsigned short* pre0 = (unsigned short*)wsb;
        unsigned short* pre1 = (unsigned short*)(wsb + PRE_B);
        unsigned short* wt   = (unsigned short*)(wsb + 2 * PRE_B);
        int*  off  = (int*)(wsb + 2 * PRE_B + WT_B);
        int*  cnt  = off + 2 * (N_NODES + 1);
        int*  bsum = cnt + 2 * N_NODES;
        int2* ep   = (int2*)(bsum + 2 * SCAN_BLOCKS);
        int*  rank = (int*)(ep + (size_t)2 * N_EDGES);

        hipMemsetAsync(cnt, 0, (size_t)2 * N_NODES * sizeof(int), stream);
        wt_build<<<128, blk, 0, stream>>>(weights, wt);
        k1_gemm_hist<<<HB_TOTAL + GEMM_BLOCKS, blk, 0, stream>>>(
            x, wt, pre0, pre1, ei0, ei1, cnt, rank, N_NODES, N_EDGES);
        scanA<<<dim3(SCAN_BLOCKS, 2), blk, 0, stream>>>(cnt, bsum);
        scanC2<<<dim3(SCAN_BLOCKS, 2), blk, 0, stream>>>(cnt, bsum, off);
        scatter_csr<<<dim3(1024, 2), blk, 0, stream>>>(ei0, ei0 + N_EDGES, v0,
                                                       ei1, ei1 + N_EDGES, v1,
                                                       off, rank, ep, N_EDGES);
        gather_fused<<<12500, blk, 0, stream>>>(off, ep, pre0, pre1, out, N_NODES);
    } else if (ws_size >= needB) {
        unsigned short* pre0 = (unsigned short*)wsb;
        unsigned short* pre1 = (unsigned short*)(wsb + PRE_B);
        unsigned short* wt   = (unsigned short*)(wsb + 2 * PRE_B);
        int*  off  = (int*)(wsb + 2 * PRE_B + WT_B);
        int*  cnt  = off + 2 * (N_NODES + 1);
        int*  bsum = cnt + 2 * N_NODES;
        int2* ep   = (int2*)(bsum + 2 * SCAN_BLOCKS);
        int*  rank = (int*)pre0;   // aliases pre0; serial: scatter before gemm

        hipMemsetAsync(cnt, 0, (size_t)2 * N_NODES * sizeof(int), stream);
        wt_build<<<128, blk, 0, stream>>>(weights, wt);
        hist_rank<<<dim3(1024, 2), blk, 0, stream>>>(ei0, ei1, cnt, rank, N_EDGES);
        scanA<<<dim3(SCAN_BLOCKS, 2), blk, 0, stream>>>(cnt, bsum);
        scanC2<<<dim3(SCAN_BLOCKS, 2), blk, 0, stream>>>(cnt, bsum, off);
        scatter_csr<<<dim3(1024, 2), blk, 0, stream>>>(ei0, ei0 + N_EDGES, v0,
                                                       ei1, ei1 + N_EDGES, v1,
                                                       off, rank, ep, N_EDGES);
        gemm_mfma2<<<GEMM_BLOCKS, blk, 0, stream>>>(x, wt, pre0, pre1, N_NODES);
        gather_fused<<<12500, blk, 0, stream>>>(off, ep, pre0, pre1, out, N_NODES);
    } else {
        // minimal sequential path
        unsigned short* pre = (unsigned short*)wsb;
        unsigned short* wt  = (unsigned short*)(wsb + PRE_B);
        int*  off  = (int*)(wsb + PRE_B + WT_B);
        int*  cnt  = off + (N_NODES + 1);
        int*  bsum = cnt + N_NODES;
        int2* ep   = (int2*)(bsum + SCAN_BLOCKS);
        int*  rank = (int*)pre;

        wt_build<<<128, blk, 0, stream>>>(weights, wt);
        const int* rows[2] = {ei0, ei1};
        const int* cols[2] = {ei0 + N_EDGES, ei1 + N_EDGES};
        const float* vals[2] = {v0, v1};
        for (int s = 0; s < 2; ++s) {
            hipMemsetAsync(cnt, 0, (size_t)N_NODES * sizeof(int), stream);
            hist_rank<<<dim3(1024, 1), blk, 0, stream>>>(rows[s], rows[s], cnt, rank, N_EDGES);
            scanA<<<dim3(SCAN_BLOCKS, 1), blk, 0, stream>>>(cnt, bsum);
            scanC2<<<dim3(SCAN_BLOCKS, 1), blk, 0, stream>>>(cnt, bsum, off);
            scatter_csr<<<dim3(1024, 1), blk, 0, stream>>>(rows[s], cols[s], vals[s],
                                                           rows[s], cols[s], vals[s],
                                                           off, rank, ep, N_EDGES);
            gemm_mfma1<<<GEMM_BLOCKS, blk, 0, stream>>>(x, wt + (size_t)s * D * D, pre, N_NODES);
            if (s == 0)
                gather_one<0><<<12500, blk, 0, stream>>>(off, ep, pre, out, N_NODES);
            else
                gather_one<1><<<12500, blk, 0, stream>>>(off, ep, pre, out, N_NODES);
        }
    }
}

// Round 11
// 147.845 us; speedup vs baseline: 1.4707x; 1.4166x over previous
//
#include <hip/hip_runtime.h>

#define N_NODES 50000
#define D 128
#define N_EDGES 800000
#define SCAN_BLOCKS ((N_NODES + 255) / 256)   // 196
#define GEMM_BLOCKS ((N_NODES + 63) / 64)     // 782
#define BINS 196                              // ceil(50000/256) row bins
#define NB1 256                               // pass-1 blocks per support
#define CH1 3125                              // edges per pass-1 block (256*3125=800000)
#define P2_CAP 9472                           // LDS staging records (75.8KB)

typedef __attribute__((ext_vector_type(8))) short short8;
typedef __attribute__((ext_vector_type(4))) float f32x4;

__device__ __forceinline__ unsigned short f2bf(float f) {
    unsigned u = __builtin_bit_cast(unsigned, f);
    u += 0x7FFFu + ((u >> 16) & 1u);
    return (unsigned short)(u >> 16);
}
__device__ __forceinline__ float bflo(unsigned p) {
    return __builtin_bit_cast(float, p << 16);
}
__device__ __forceinline__ float bfhi(unsigned p) {
    return __builtin_bit_cast(float, p & 0xFFFF0000u);
}

// ---- build wt[s][c][k] bf16 (transposed, c-major) from w[s][k][c] f32 ----
__global__ __launch_bounds__(256) void wt_build(const float* __restrict__ w,
                                                unsigned short* __restrict__ wt) {
    int i = blockIdx.x * 256 + threadIdx.x;
    if (i < 2 * D * D) {
        int s = i >> 14, rem = i & 16383, c = rem >> 7, k = rem & 127;
        wt[i] = f2bf(w[s * D * D + k * D + c]);
    }
}

// ---- gemm body: pre_s = bf16(x @ W_s) for 64 rows starting blk*64 ----
template<int NS>
__device__ __forceinline__ void gemm_body(const float* __restrict__ x,
                                          const unsigned short* __restrict__ wt,
                                          unsigned short* __restrict__ pre0,
                                          unsigned short* __restrict__ pre1,
                                          int n_rows, int blk) {
    const int lane = threadIdx.x & 63;
    const int wid  = threadIdx.x >> 6;
    const int q    = lane >> 4;
    const int rlo  = lane & 15;
    const int r0   = blk * 64 + wid * 16;
    if (r0 >= n_rows) return;

    const float4* x4 = (const float4*)x;
    int arow  = r0 + rlo;
    int arowc = arow < n_rows ? arow : n_rows - 1;

    short8 afr[4];
    #pragma unroll
    for (int kb = 0; kb < 4; ++kb) {
        float4 fa = x4[(size_t)arowc * 32 + kb * 8 + q * 2];
        float4 fb = x4[(size_t)arowc * 32 + kb * 8 + q * 2 + 1];
        short8 a;
        a[0] = (short)f2bf(fa.x); a[1] = (short)f2bf(fa.y);
        a[2] = (short)f2bf(fa.z); a[3] = (short)f2bf(fa.w);
        a[4] = (short)f2bf(fb.x); a[5] = (short)f2bf(fb.y);
        a[6] = (short)f2bf(fb.z); a[7] = (short)f2bf(fb.w);
        afr[kb] = a;
    }

    const short8* wt8 = (const short8*)wt;
    f32x4 acc[NS][8];
    #pragma unroll
    for (int s = 0; s < NS; ++s)
        #pragma unroll
        for (int t = 0; t < 8; ++t)
            acc[s][t] = (f32x4){0.f, 0.f, 0.f, 0.f};

    #pragma unroll
    for (int t = 0; t < 8; ++t) {
        int c = t * 16 + rlo;
        #pragma unroll
        for (int kb = 0; kb < 4; ++kb) {
            short8 b0 = wt8[(size_t)c * 16 + kb * 4 + q];
            acc[0][t] = __builtin_amdgcn_mfma_f32_16x16x32_bf16(afr[kb], b0, acc[0][t], 0, 0, 0);
            if (NS == 2) {
                short8 b1 = wt8[(size_t)(D + c) * 16 + kb * 4 + q];
                acc[1][t] = __builtin_amdgcn_mfma_f32_16x16x32_bf16(afr[kb], b1, acc[1][t], 0, 0, 0);
            }
        }
    }

    #pragma unroll
    for (int i = 0; i < 4; ++i) {
        int rw = r0 + q * 4 + i;
        if (rw < n_rows) {
            #pragma unroll
            for (int t = 0; t < 8; ++t) {
                pre0[(size_t)rw * D + t * 16 + rlo] = f2bf(acc[0][t][i]);
                if (NS == 2) pre1[(size_t)rw * D + t * 16 + rlo] = f2bf(acc[1][t][i]);
            }
        }
    }
}

// ======================= radix CSR build (no global atomics) =======================

// p1: LDS histogram of row>>8 per (support, block of CH1 edges) -> h[s][blk][bin]
__global__ __launch_bounds__(256) void p1_count(const int* __restrict__ r0,
                                                const int* __restrict__ r1,
                                                int* __restrict__ h) {
    int s = blockIdx.y, blk = blockIdx.x;
    const int* r = s ? r1 : r0;
    __shared__ int hist[BINS];
    for (int i = threadIdx.x; i < BINS; i += 256) hist[i] = 0;
    __syncthreads();
    int start = blk * CH1, end = start + CH1;
    for (int e = start + (int)threadIdx.x; e < end; e += 256)
        atomicAdd(&hist[r[e] >> 8], 1);
    __syncthreads();
    for (int i = threadIdx.x; i < BINS; i += 256)
        h[(size_t)(s * NB1 + blk) * BINS + i] = hist[i];
}

// binred: bintot[s][bin] = sum over blocks of h[s][blk][bin]
__global__ __launch_bounds__(256) void binred(const int* __restrict__ h,
                                              int* __restrict__ bintot) {
    int s = blockIdx.y, bin = blockIdx.x, t = threadIdx.x;
    int v = h[(size_t)(s * NB1 + t) * BINS + bin];
    const int lane = t & 63, wid = t >> 6;
    __shared__ int ws[4];
    #pragma unroll
    for (int o = 32; o > 0; o >>= 1) v += __shfl_down(v, o);
    if (lane == 0) ws[wid] = v;
    __syncthreads();
    if (t == 0) bintot[s * BINS + bin] = ws[0] + ws[1] + ws[2] + ws[3];
}

// binscan: exclusive scan of bintot -> binbase[s][0..BINS] (sentinel = total)
__global__ __launch_bounds__(256) void binscan(const int* __restrict__ bintot,
                                               int* __restrict__ binbase) {
    int s = blockIdx.x, t = threadIdx.x;
    int v = (t < BINS) ? bintot[s * BINS + t] : 0;
    const int lane = t & 63, wid = t >> 6;
    __shared__ int ws[4];
    int incl = v;
    #pragma unroll
    for (int o = 1; o < 64; o <<= 1) { int tv = __shfl_up(incl, o); if (lane >= o) incl += tv; }
    if (lane == 63) ws[wid] = incl;
    __syncthreads();
    int wbase = 0;
    #pragma unroll
    for (int j = 0; j < 4; ++j) wbase += (j < wid) ? ws[j] : 0;
    int excl = wbase + incl - v;
    if (t < BINS) binbase[s * (BINS + 1) + t] = excl;
    if (t == BINS - 1) binbase[s * (BINS + 1) + BINS] = excl + v;
}

// blkscan: h[s][blk][bin] = binbase[s][bin] + exclusive-scan-over-blk(counts)
__global__ __launch_bounds__(256) void blkscan(int* __restrict__ h,
                                               const int* __restrict__ binbase) {
    int s = blockIdx.y, bin = blockIdx.x, t = threadIdx.x;
    size_t idx = (size_t)(s * NB1 + t) * BINS + bin;
    int v = h[idx];
    const int lane = t & 63, wid = t >> 6;
    __shared__ int ws[4];
    int incl = v;
    #pragma unroll
    for (int o = 1; o < 64; o <<= 1) { int tv = __shfl_up(incl, o); if (lane >= o) incl += tv; }
    if (lane == 63) ws[wid] = incl;
    __syncthreads();
    int wbase = 0;
    #pragma unroll
    for (int j = 0; j < 4; ++j) wbase += (j < wid) ? ws[j] : 0;
    h[idx] = binbase[s * (BINS + 1) + bin] + (wbase + incl - v);
}

// k_fill_gemm: [fill blocks (bin-scatter via LDS ranks) | gemm blocks]
__global__ __launch_bounds__(256) void k_fill_gemm(const float* __restrict__ x,
                                                   const unsigned short* __restrict__ wt,
                                                   unsigned short* __restrict__ pre0,
                                                   unsigned short* __restrict__ pre1,
                                                   const int* __restrict__ r0, const int* __restrict__ c0,
                                                   const float* __restrict__ v0,
                                                   const int* __restrict__ r1, const int* __restrict__ c1,
                                                   const float* __restrict__ v1,
                                                   const int* __restrict__ h,
                                                   int2* __restrict__ rec, int n_rows) {
    int bid = blockIdx.x;
    if (bid < 2 * NB1) {
        int s = bid & 1, blk = bid >> 1;
        const int*   r = s ? r1 : r0;
        const int*   c = s ? c1 : c0;
        const float* v = s ? v1 : v0;
        int2* rs = rec + (size_t)s * N_EDGES;
        __shared__ int base[BINS];
        __shared__ int cnt2[BINS];
        for (int i = threadIdx.x; i < BINS; i += 256) {
            base[i] = h[(size_t)(s * NB1 + blk) * BINS + i];
            cnt2[i] = 0;
        }
        __syncthreads();
        int start = blk * CH1, end = start + CH1;
        for (int e = start + (int)threadIdx.x; e < end; e += 256) {
            int rr = r[e], cc = c[e];
            float vv = v[e];
            int bin = rr >> 8;
            int lr = atomicAdd(&cnt2[bin], 1);
            rs[base[bin] + lr] = make_int2((cc << 8) | (rr & 255), __float_as_int(vv));
        }
    } else {
        gemm_body<2>(x, wt, pre0, pre1, n_rows, bid - 2 * NB1);
    }
}

// p2: per (bin,support): LDS count+scan over 256 rows -> off[]; write row-grouped ep
__global__ __launch_bounds__(256) void p2_sort(const int* __restrict__ binbase,
                                               const int2* __restrict__ rec,
                                               int2* __restrict__ ep,
                                               int* __restrict__ off) {
    int s = blockIdx.y, bin = blockIdx.x, t = threadIdx.x;
    int bs  = binbase[s * (BINS + 1) + bin];
    int be  = binbase[s * (BINS + 1) + bin + 1];
    int cnt = be - bs;
    const int2* rs = rec + (size_t)s * N_EDGES;
    int2* es = ep + (size_t)s * N_EDGES;
    __shared__ int  lc[256];
    __shared__ int  cur[256];
    __shared__ int  ws[4];
    __shared__ int2 stage[P2_CAP];
    lc[t] = 0;
    __syncthreads();
    bool staged = (cnt <= P2_CAP);
    for (int i = t; i < cnt; i += 256) {
        int2 R = rs[bs + i];
        if (staged) stage[i] = R;
        atomicAdd(&lc[R.x & 255], 1);
    }
    __syncthreads();
    int v = lc[t];
    const int lane = t & 63, wid = t >> 6;
    int incl = v;
    #pragma unroll
    for (int o = 1; o < 64; o <<= 1) { int tv = __shfl_up(incl, o); if (lane >= o) incl += tv; }
    if (lane == 63) ws[wid] = incl;
    __syncthreads();
    int wbase = 0;
    #pragma unroll
    for (int j = 0; j < 4; ++j) wbase += (j < wid) ? ws[j] : 0;
    int excl = wbase + incl - v;
    int row = bin * 256 + t;
    if (row < N_NODES) off[s * (N_NODES + 1) + row] = bs + excl;
    if (bin == 0 && t == 0) off[s * (N_NODES + 1) + N_NODES] = N_EDGES;
    cur[t] = excl;
    __syncthreads();
    for (int i = t; i < cnt; i += 256) {
        int2 R = staged ? stage[i] : rs[bs + i];
        int p = atomicAdd(&cur[R.x & 255], 1);
        es[bs + p] = make_int2(R.x >> 8, R.y);
    }
}

// ======================= gather (unchanged, proven) =======================
__device__ __forceinline__ void row_acc(const int2* __restrict__ ep,
                                        const unsigned short* __restrict__ pre,
                                        int b, int e, int lane, float& ax, float& ay) {
    int i = b;
    for (; i + 7 < e; i += 8) {
        int2 E[8];
        unsigned P[8];
        #pragma unroll
        for (int j = 0; j < 8; ++j) E[j] = ep[i + j];
        #pragma unroll
        for (int j = 0; j < 8; ++j) P[j] = *(const unsigned*)(pre + (size_t)E[j].x * D + 2 * lane);
        #pragma unroll
        for (int j = 0; j < 8; ++j) {
            float w = __int_as_float(E[j].y);
            ax = fmaf(w, bflo(P[j]), ax);
            ay = fmaf(w, bfhi(P[j]), ay);
        }
    }
    if (i + 3 < e) {
        int2 E[4];
        unsigned P[4];
        #pragma unroll
        for (int j = 0; j < 4; ++j) E[j] = ep[i + j];
        #pragma unroll
        for (int j = 0; j < 4; ++j) P[j] = *(const unsigned*)(pre + (size_t)E[j].x * D + 2 * lane);
        #pragma unroll
        for (int j = 0; j < 4; ++j) {
            float w = __int_as_float(E[j].y);
            ax = fmaf(w, bflo(P[j]), ax);
            ay = fmaf(w, bfhi(P[j]), ay);
        }
        i += 4;
    }
    for (; i < e; ++i) {
        int2 e0 = ep[i];
        float w = __int_as_float(e0.y);
        unsigned p = *(const unsigned*)(pre + (size_t)e0.x * D + 2 * lane);
        ax = fmaf(w, bflo(p), ax);
        ay = fmaf(w, bfhi(p), ay);
    }
}

__global__ __launch_bounds__(256) void gather_fused(const int* __restrict__ off_base,
                                                    const int2* __restrict__ ep_base,
                                                    const unsigned short* __restrict__ pre0,
                                                    const unsigned short* __restrict__ pre1,
                                                    float* __restrict__ out, int n_rows) {
    const int lane = threadIdx.x & 63;
    const int wid  = threadIdx.x >> 6;
    const int wpg  = 4 * gridDim.x;
    const int2* ep1b = ep_base + N_EDGES;
    const int* o1 = off_base + (N_NODES + 1);
    float2* out2 = (float2*)out;
    for (int r = blockIdx.x * 4 + wid; r < n_rows; r += wpg) {
        float ax0 = 0.f, ay0 = 0.f, ax1 = 0.f, ay1 = 0.f;
        int i0 = off_base[r], e0 = off_base[r + 1];
        int i1 = o1[r],       e1 = o1[r + 1];
        while (i0 + 7 < e0 && i1 + 7 < e1) {
            int2 E0[8], E1[8];
            unsigned P0[8], P1[8];
            #pragma unroll
            for (int j = 0; j < 8; ++j) { E0[j] = ep_base[i0 + j]; E1[j] = ep1b[i1 + j]; }
            #pragma unroll
            for (int j = 0; j < 8; ++j) {
                P0[j] = *(const unsigned*)(pre0 + (size_t)E0[j].x * D + 2 * lane);
                P1[j] = *(const unsigned*)(pre1 + (size_t)E1[j].x * D + 2 * lane);
            }
            #pragma unroll
            for (int j = 0; j < 8; ++j) {
                float w0 = __int_as_float(E0[j].y);
                float w1 = __int_as_float(E1[j].y);
                ax0 = fmaf(w0, bflo(P0[j]), ax0);
                ay0 = fmaf(w0, bfhi(P0[j]), ay0);
                ax1 = fmaf(w1, bflo(P1[j]), ax1);
                ay1 = fmaf(w1, bfhi(P1[j]), ay1);
            }
            i0 += 8; i1 += 8;
        }
        row_acc(ep_base, pre0, i0, e0, lane, ax0, ay0);
        row_acc(ep1b,    pre1, i1, e1, lane, ax1, ay1);
        float2 o;
        o.x = fmaxf(ax0 + ax1, 0.f);
        o.y = fmaxf(ay0 + ay1, 0.f);
        out2[(size_t)r * 64 + lane] = o;
    }
}

// ======================= fallback path (proven R10 pieces) =======================
__global__ __launch_bounds__(256) void gemm_mfma2(const float* __restrict__ x,
                                                  const unsigned short* __restrict__ wt,
                                                  unsigned short* __restrict__ pre0,
                                                  unsigned short* __restrict__ pre1, int n_rows) {
    gemm_body<2>(x, wt, pre0, pre1, n_rows, blockIdx.x);
}
__global__ __launch_bounds__(256) void gemm_mfma1(const float* __restrict__ x,
                                                  const unsigned short* __restrict__ wt,
                                                  unsigned short* __restrict__ pre, int n_rows) {
    gemm_body<1>(x, wt, pre, pre, n_rows, blockIdx.x);
}

__global__ __launch_bounds__(256) void hist_rank(const int* __restrict__ r0,
                                                 const int* __restrict__ r1,
                                                 int* __restrict__ cnt_base,
                                                 int* __restrict__ rank_base, int n_edges) {
    int s = blockIdx.y;
    const int* r = s ? r1 : r0;
    int* cnt  = cnt_base + s * N_NODES;
    int* rank = rank_base + (size_t)s * N_EDGES;
    for (int e = blockIdx.x * 256 + threadIdx.x; e < n_edges; e += gridDim.x * 256)
        rank[e] = atomicAdd(&cnt[r[e]], 1);
}

__global__ __launch_bounds__(256) void scanA(const int* __restrict__ cnt_base,
                                             int* __restrict__ bsum) {
    int s = blockIdx.y;
    int i = blockIdx.x * 256 + threadIdx.x;
    int v = (i < N_NODES) ? cnt_base[s * N_NODES + i] : 0;
    const int lane = threadIdx.x & 63;
    const int wid  = threadIdx.x >> 6;
    __shared__ int ws[4];
    #pragma unroll
    for (int off = 32; off > 0; off >>= 1) v += __shfl_down(v, off);
    if (lane == 0) ws[wid] = v;
    __syncthreads();
    if (threadIdx.x == 0)
        bsum[s * SCAN_BLOCKS + blockIdx.x] = ws[0] + ws[1] + ws[2] + ws[3];
}

__global__ __launch_bounds__(256) void scanC2(const int* __restrict__ cnt_base,
                                              const int* __restrict__ bsum,
                                              int* __restrict__ off_base) {
    int s = blockIdx.y;
    int t = threadIdx.x;
    const int lane = t & 63;
    const int wid  = t >> 6;
    __shared__ int ws[4];
    __shared__ int base_s;
    int bv = (t < (int)blockIdx.x && t < SCAN_BLOCKS) ? bsum[s * SCAN_BLOCKS + t] : 0;
    #pragma unroll
    for (int off = 32; off > 0; off >>= 1) bv += __shfl_down(bv, off);
    if (lane == 0) ws[wid] = bv;
    __syncthreads();
    if (t == 0) base_s = ws[0] + ws[1] + ws[2] + ws[3];
    __syncthreads();
    int base = base_s;
    __syncthreads();
    int i = blockIdx.x * 256 + t;
    int v = (i < N_NODES) ? cnt_base[s * N_NODES + i] : 0;
    int incl = v;
    #pragma unroll
    for (int off = 1; off < 64; off <<= 1) {
        int tv = __shfl_up(incl, off);
        if (lane >= off) incl += tv;
    }
    if (lane == 63) ws[wid] = incl;
    __syncthreads();
    int wbase = 0;
    #pragma unroll
    for (int j = 0; j < 4; ++j) wbase += (j < wid) ? ws[j] : 0;
    int* off = off_base + s * (N_NODES + 1);
    if (i < N_NODES)
        off[i] = base + wbase + incl - v;
    if (blockIdx.x == 0 && t == 0)
        off[N_NODES] = N_EDGES;
}

__global__ __launch_bounds__(256) void scatter_csr(const int* __restrict__ r0, const int* __restrict__ c0,
                                                   const float* __restrict__ v0,
                                                   const int* __restrict__ r1, const int* __restrict__ c1,
                                                   const float* __restrict__ v1,
                                                   const int* __restrict__ off_base,
                                                   const int* __restrict__ rank_base,
                                                   int2* __restrict__ ep_base, int n_edges) {
    int s = blockIdx.y;
    const int*   r    = s ? r1 : r0;
    const int*   c    = s ? c1 : c0;
    const float* v    = s ? v1 : v0;
    const int*   off  = off_base + s * (N_NODES + 1);
    const int*   rank = rank_base + (size_t)s * N_EDGES;
    int2* ep = ep_base + (size_t)s * N_EDGES;
    for (int e = blockIdx.x * 256 + threadIdx.x; e < n_edges; e += gridDim.x * 256) {
        int p = off[r[e]] + rank[e];
        int2 rec;
        rec.x = c[e];
        rec.y = __float_as_int(v[e]);
        ep[p] = rec;
    }
}

template<int ACCUM_RELU>
__global__ __launch_bounds__(256) void gather_one(const int* __restrict__ off,
                                                  const int2* __restrict__ ep,
                                                  const unsigned short* __restrict__ pre,
                                                  float* __restrict__ out, int n_rows) {
    const int lane = threadIdx.x & 63;
    const int wid  = threadIdx.x >> 6;
    const int wpg  = 4 * gridDim.x;
    float2* out2 = (float2*)out;
    for (int r = blockIdx.x * 4 + wid; r < n_rows; r += wpg) {
        float ax = 0.f, ay = 0.f;
        row_acc(ep, pre, off[r], off[r + 1], lane, ax, ay);
        float2 o;
        if (ACCUM_RELU) {
            float2 prev = out2[(size_t)r * 64 + lane];
            o.x = fmaxf(prev.x + ax, 0.f);
            o.y = fmaxf(prev.y + ay, 0.f);
        } else {
            o.x = ax; o.y = ay;
        }
        out2[(size_t)r * 64 + lane] = o;
    }
}

extern "C" void kernel_launch(void* const* d_in, const int* in_sizes, int n_in,
                              void* d_out, int out_size, void* d_ws, size_t ws_size,
                              hipStream_t stream) {
    const float* x       = (const float*)d_in[0];
    const float* weights = (const float*)d_in[1];
    const int*   ei0     = (const int*)d_in[2];
    const float* v0      = (const float*)d_in[3];
    const int*   ei1     = (const int*)d_in[4];
    const float* v1      = (const float*)d_in[5];
    float* out = (float*)d_out;

    dim3 blk(256);
    const size_t PRE_B = (size_t)N_NODES * D * sizeof(unsigned short);  // 12.8 MB
    const size_t WT_B  = (size_t)2 * D * D * sizeof(unsigned short);    // 64 KB
    const size_t H_B   = (size_t)2 * NB1 * BINS * 4;                    // 401 KB
    const size_t BT_B  = (size_t)2 * BINS * 4;
    const size_t BB_B  = (size_t)2 * (BINS + 1) * 4;
    const size_t OFF_B = (size_t)2 * (N_NODES + 1) * 4;
    const size_t E8    = (size_t)2 * N_EDGES * sizeof(int2);            // 12.8 MB

    char* wsb = (char*)d_ws;
    // NEW tier: pre0, pre1, wt, h, bintot, binbase, off, rec, ep  (~52.1 MB)
    size_t needNew = 2 * PRE_B + WT_B + H_B + BT_B + BB_B + OFF_B + 2 * E8;
    // fallback tier (R10-A1 style, ~45.7 MB)
    size_t needA1 = 2 * PRE_B + WT_B
                  + (size_t)(2 * (N_NODES + 1) + 2 * N_NODES + 2 * SCAN_BLOCKS) * 4
                  + E8 + (size_t)2 * N_EDGES * 4;

    if (ws_size >= needNew) {
        unsigned short* pre0 = (unsigned short*)wsb;
        unsigned short* pre1 = (unsigned short*)(wsb + PRE_B);
        unsigned short* wt   = (unsigned short*)(wsb + 2 * PRE_B);
        int*  h       = (int*)(wsb + 2 * PRE_B + WT_B);
        int*  bintot  = (int*)((char*)h + H_B);
        int*  binbase = (int*)((char*)bintot + BT_B);
        int*  off     = (int*)((char*)binbase + BB_B);
        int2* rec     = (int2*)((char*)off + OFF_B);
        int2* ep      = rec + (size_t)2 * N_EDGES;

        wt_build<<<128, blk, 0, stream>>>(weights, wt);
        p1_count<<<dim3(NB1, 2), blk, 0, stream>>>(ei0, ei1, h);
        binred  <<<dim3(BINS, 2), blk, 0, stream>>>(h, bintot);
        binscan <<<2, blk, 0, stream>>>(bintot, binbase);
        blkscan <<<dim3(BINS, 2), blk, 0, stream>>>(h, binbase);
        k_fill_gemm<<<2 * NB1 + GEMM_BLOCKS, blk, 0, stream>>>(
            x, wt, pre0, pre1,
            ei0, ei0 + N_EDGES, v0, ei1, ei1 + N_EDGES, v1,
            h, rec, N_NODES);
        p2_sort<<<dim3(BINS, 2), blk, 0, stream>>>(binbase, rec, ep, off);
        gather_fused<<<12500, blk, 0, stream>>>(off, ep, pre0, pre1, out, N_NODES);
    } else if (ws_size >= needA1) {
        unsigned short* pre0 = (unsigned short*)wsb;
        unsigned short* pre1 = (unsigned short*)(wsb + PRE_B);
        unsigned short* wt   = (unsigned short*)(wsb + 2 * PRE_B);
        int*  off  = (int*)(wsb + 2 * PRE_B + WT_B);
        int*  cnt  = off + 2 * (N_NODES + 1);
        int*  bsum = cnt + 2 * N_NODES;
        int2* ep   = (int2*)(bsum + 2 * SCAN_BLOCKS);
        int*  rank = (int*)(ep + (size_t)2 * N_EDGES);

        hipMemsetAsync(cnt, 0, (size_t)2 * N_NODES * sizeof(int), stream);
        wt_build<<<128, blk, 0, stream>>>(weights, wt);
        hist_rank<<<dim3(1024, 2), blk, 0, stream>>>(ei0, ei1, cnt, rank, N_EDGES);
        gemm_mfma2<<<GEMM_BLOCKS, blk, 0, stream>>>(x, wt, pre0, pre1, N_NODES);
        scanA<<<dim3(SCAN_BLOCKS, 2), blk, 0, stream>>>(cnt, bsum);
        scanC2<<<dim3(SCAN_BLOCKS, 2), blk, 0, stream>>>(cnt, bsum, off);
        scatter_csr<<<dim3(1024, 2), blk, 0, stream>>>(ei0, ei0 + N_EDGES, v0,
                                                       ei1, ei1 + N_EDGES, v1,
                                                       off, rank, ep, N_EDGES);
        gather_fused<<<12500, blk, 0, stream>>>(off, ep, pre0, pre1, out, N_NODES);
    } else {
        // minimal sequential path
        unsigned short* pre = (unsigned short*)wsb;
        unsigned short* wt  = (unsigned short*)(wsb + PRE_B);
        int*  off  = (int*)(wsb + PRE_B + WT_B);
        int*  cnt  = off + (N_NODES + 1);
        int*  bsum = cnt + N_NODES;
        int2* ep   = (int2*)(bsum + SCAN_BLOCKS);
        int*  rank = (int*)pre;

        wt_build<<<128, blk, 0, stream>>>(weights, wt);
        const int* rows[2] = {ei0, ei1};
        const int* cols[2] = {ei0 + N_EDGES, ei1 + N_EDGES};
        const float* vals[2] = {v0, v1};
        for (int s = 0; s < 2; ++s) {
            hipMemsetAsync(cnt, 0, (size_t)N_NODES * sizeof(int), stream);
            hist_rank<<<dim3(1024, 1), blk, 0, stream>>>(rows[s], rows[s], cnt, rank, N_EDGES);
            scanA<<<dim3(SCAN_BLOCKS, 1), blk, 0, stream>>>(cnt, bsum);
            scanC2<<<dim3(SCAN_BLOCKS, 1), blk, 0, stream>>>(cnt, bsum, off);
            scatter_csr<<<dim3(1024, 1), blk, 0, stream>>>(rows[s], cols[s], vals[s],
                                                           rows[s], cols[s], vals[s],
                                                           off, rank, ep, N_EDGES);
            gemm_mfma1<<<GEMM_BLOCKS, blk, 0, stream>>>(x, wt + (size_t)s * D * D, pre, N_NODES);
            if (s == 0)
                gather_one<0><<<12500, blk, 0, stream>>>(off, ep, pre, out, N_NODES);
            else
                gather_one<1><<<12500, blk, 0, stream>>>(off, ep, pre, out, N_NODES);
        }
    }
}